// Round 1
// baseline (264.975 us; speedup 1.0000x reference)
//
#include <hip/hip_runtime.h>
#include <stdint.h>

#define B_SZ   2048
#define IN_SZ  1024
#define OUT_SZ 1024
#define Q_SZ   16
#define K_EXP  (Q_SZ * IN_SZ)   // 16384

typedef __attribute__((ext_vector_type(8))) short short8;   // 8 bf16 (4 VGPRs)
typedef __attribute__((ext_vector_type(4))) float floatx4;  // MFMA accumulator

__device__ __forceinline__ unsigned short f32_to_bf16_rne(float f) {
    union { float f; uint32_t u; } v; v.f = f;
    uint32_t u = v.u;
    return (unsigned short)((u + 0x7FFFu + ((u >> 16) & 1u)) >> 16);
}

__device__ __forceinline__ void gll16(const void* g, void* l) {
    // async global->LDS, 16B/lane; LDS dst is wave-uniform base + lane*16
    __builtin_amdgcn_global_load_lds(
        (const __attribute__((address_space(1))) void*)g,
        (__attribute__((address_space(3))) void*)l, 16, 0, 0);
}

// ---------------- prep 1: out[b][o] = bias[o] ----------------
__global__ void k_init_out(float* __restrict__ out, const float* __restrict__ bias) {
    int t = blockIdx.x * 256 + threadIdx.x;        // float4 index, 524288 total
    const float4* b4 = (const float4*)bias;
    ((float4*)out)[t] = b4[t & 255];               // 256 float4 per row of 1024
}

// ---------------- prep 2: A_exp[b][q*IN+i] = (idx==q) ? bf16(x) : 0 ----------------
__global__ void k_build_a(const float* __restrict__ x, const int* __restrict__ idx,
                          unsigned short* __restrict__ A) {
    int t = blockIdx.x * 256 + threadIdx.x;        // 262144 threads, 8 i's each
    int b  = t >> 7;
    int ic = (t & 127) << 3;
    const float* xp = x + (size_t)b * IN_SZ + ic;
    const int*   ip = idx + (size_t)b * IN_SZ + ic;
    float xv[8]; int iv[8];
    *(float4*)(xv)     = ((const float4*)xp)[0];
    *(float4*)(xv + 4) = ((const float4*)xp)[1];
    *(int4*)(iv)       = ((const int4*)ip)[0];
    *(int4*)(iv + 4)   = ((const int4*)ip)[1];
    unsigned short bf[8];
#pragma unroll
    for (int j = 0; j < 8; ++j) bf[j] = f32_to_bf16_rne(xv[j]);
    unsigned short* Ab = A + (size_t)b * K_EXP + ic;
#pragma unroll
    for (int q = 0; q < Q_SZ; ++q) {
        unsigned short ov[8];
#pragma unroll
        for (int j = 0; j < 8; ++j) ov[j] = (iv[j] == q) ? bf[j] : (unsigned short)0;
        *(uint4*)(Ab + q * IN_SZ) = *(uint4*)ov;   // 16B aligned (ic mult of 8)
    }
}

// ---------------- prep 3: Wt[o][q*IN+i] = bf16(W[q*IN+i][o])  (transpose+convert) ----
__global__ void k_build_wt(const float* __restrict__ W, unsigned short* __restrict__ Wt) {
    __shared__ float tile[64][65];                 // +1 pad breaks bank conflicts
    int t = threadIdx.x;
    int k0 = blockIdx.x * 64;                      // 256 k-tiles
    int o0 = blockIdx.y * 64;                      // 16 o-tiles
#pragma unroll
    for (int it = 0; it < 4; ++it) {
        int F = it * 256 + t;                      // 1024 float4 loads
        int row = F >> 4;
        int c4  = (F & 15) * 4;
        float4 v = *(const float4*)(W + (size_t)(k0 + row) * OUT_SZ + o0 + c4);
        tile[row][c4 + 0] = v.x; tile[row][c4 + 1] = v.y;
        tile[row][c4 + 2] = v.z; tile[row][c4 + 3] = v.w;
    }
    __syncthreads();
#pragma unroll
    for (int it = 0; it < 2; ++it) {
        int G = it * 256 + t;                      // 512 uint4 stores
        int oo = G >> 3;
        int kc = (G & 7) * 8;
        unsigned short ov[8];
#pragma unroll
        for (int j = 0; j < 8; ++j) ov[j] = f32_to_bf16_rne(tile[kc + j][oo]);
        *(uint4*)(Wt + (size_t)(o0 + oo) * K_EXP + k0 + kc) = *(uint4*)ov;
    }
}

// ---------------- main GEMM: out += A_exp @ Wt^T, split-K=4, atomic epilogue --------
#define KSPLIT 4
#define KPER   (K_EXP / KSPLIT)                    // 4096 -> 128 k-steps of 32

__global__ __launch_bounds__(256) void k_gemm(const unsigned short* __restrict__ A,
                                              const unsigned short* __restrict__ Wt,
                                              float* __restrict__ out) {
    __shared__ unsigned short Alds[128 * 32];      // 8 KB, rows of 64B (k-contig)
    __shared__ unsigned short Blds[128 * 32];      // 8 KB
    int tid  = threadIdx.x;
    int wave = tid >> 6, lane = tid & 63;
    int wm = wave & 1, wn = wave >> 1;             // 2x2 wave grid, 64x64 each
    int b0 = blockIdx.y * 128;
    int o0 = blockIdx.x * 128;
    int kbase = blockIdx.z * KPER;

    // staging: chunk = round*256 + wave*64 + lane; row = chunk>>2; col16 = chunk&3
    int r0 = wave * 16 + (lane >> 2);
    int cc = lane & 3;
    const unsigned short* aSrc0 = A  + (size_t)(b0 + r0) * K_EXP + cc * 8 + kbase;
    const unsigned short* aSrc1 = aSrc0 + (size_t)64 * K_EXP;
    const unsigned short* bSrc0 = Wt + (size_t)(o0 + r0) * K_EXP + cc * 8 + kbase;
    const unsigned short* bSrc1 = bSrc0 + (size_t)64 * K_EXP;
    char* aDst0 = (char*)Alds + wave * 1024;       // wave-uniform LDS bases
    char* aDst1 = aDst0 + 4096;
    char* bDst0 = (char*)Blds + wave * 1024;
    char* bDst1 = bDst0 + 4096;

    floatx4 acc[16];
#pragma unroll
    for (int i = 0; i < 16; ++i) acc[i] = (floatx4){0.f, 0.f, 0.f, 0.f};

    // fragment read offsets: A[m=lane&15][k=(lane>>4)*8+j], same for B with n
    const char* aB = (const char*)Alds;
    const char* bB = (const char*)Blds;
    int aoff[4], boff[4];
#pragma unroll
    for (int mt = 0; mt < 4; ++mt)
        aoff[mt] = (wm * 64 + mt * 16 + (lane & 15)) * 64 + (lane >> 4) * 16;
#pragma unroll
    for (int nt = 0; nt < 4; ++nt)
        boff[nt] = (wn * 64 + nt * 16 + (lane & 15)) * 64 + (lane >> 4) * 16;

    for (int step = 0; step < KPER / 32; ++step) {
        int ko = step * 32;
        gll16(aSrc0 + ko, aDst0);
        gll16(aSrc1 + ko, aDst1);
        gll16(bSrc0 + ko, bDst0);
        gll16(bSrc1 + ko, bDst1);
        __syncthreads();                            // drains vmcnt before barrier
        short8 aF[4], bF[4];
#pragma unroll
        for (int mt = 0; mt < 4; ++mt) aF[mt] = *(const short8*)(aB + aoff[mt]);
#pragma unroll
        for (int nt = 0; nt < 4; ++nt) bF[nt] = *(const short8*)(bB + boff[nt]);
#pragma unroll
        for (int mt = 0; mt < 4; ++mt)
#pragma unroll
            for (int nt = 0; nt < 4; ++nt)
                acc[mt * 4 + nt] = __builtin_amdgcn_mfma_f32_16x16x32_bf16(
                    aF[mt], bF[nt], acc[mt * 4 + nt], 0, 0, 0);
        __syncthreads();
    }

    // epilogue: C/D layout col=lane&15 (o), row=(lane>>4)*4+reg (b)
    int cn = lane & 15, rq = lane >> 4;
#pragma unroll
    for (int mt = 0; mt < 4; ++mt)
#pragma unroll
        for (int nt = 0; nt < 4; ++nt) {
            int bb = b0 + wm * 64 + mt * 16 + rq * 4;
            int oo = o0 + wn * 64 + nt * 16 + cn;
#pragma unroll
            for (int e = 0; e < 4; ++e)
                atomicAdd(out + (size_t)(bb + e) * OUT_SZ + oo, acc[mt * 4 + nt][e]);
        }
}

// ---------------- fallback (ws too small): exact fp32 gather ----------------
__global__ void k_naive(const float* __restrict__ x, const int* __restrict__ idx,
                        const float* __restrict__ W, const float* __restrict__ bias,
                        float* __restrict__ out) {
    int b = blockIdx.x;
    int o = threadIdx.x * 4;
    float4 acc = *(const float4*)(bias + o);
    const float* xr = x + (size_t)b * IN_SZ;
    const int*   ir = idx + (size_t)b * IN_SZ;
    for (int i = 0; i < IN_SZ; ++i) {
        float xv = xr[i];
        int q = ir[i];
        float4 w4 = *(const float4*)(W + ((size_t)q * IN_SZ + i) * OUT_SZ + o);
        acc.x += xv * w4.x; acc.y += xv * w4.y;
        acc.z += xv * w4.z; acc.w += xv * w4.w;
    }
    *(float4*)(out + (size_t)b * OUT_SZ + o) = acc;
}

extern "C" void kernel_launch(void* const* d_in, const int* in_sizes, int n_in,
                              void* d_out, int out_size, void* d_ws, size_t ws_size,
                              hipStream_t stream) {
    const float* x    = (const float*)d_in[0];
    const int*   idx  = (const int*)d_in[1];
    const float* W    = (const float*)d_in[2];
    const float* bias = (const float*)d_in[3];
    float* out = (float*)d_out;

    const size_t wt_elems = (size_t)OUT_SZ * K_EXP;          // 16M ushorts = 32 MB
    const size_t a_elems  = (size_t)B_SZ * K_EXP;            // 32M ushorts = 64 MB
    if (ws_size < (wt_elems + a_elems) * sizeof(unsigned short)) {
        k_naive<<<dim3(B_SZ), dim3(256), 0, stream>>>(x, idx, W, bias, out);
        return;
    }
    unsigned short* Wt = (unsigned short*)d_ws;
    unsigned short* A  = Wt + wt_elems;

    k_init_out<<<dim3(2048), dim3(256), 0, stream>>>(out, bias);
    k_build_a<<<dim3(1024), dim3(256), 0, stream>>>(x, idx, A);
    k_build_wt<<<dim3(256, 16), dim3(256), 0, stream>>>(W, Wt);
    k_gemm<<<dim3(OUT_SZ / 128, B_SZ / 128, KSPLIT), dim3(256), 0, stream>>>(A, Wt, out);
}

// Round 2
// 262.889 us; speedup vs baseline: 1.0079x; 1.0079x over previous
//
#include <hip/hip_runtime.h>
#include <stdint.h>

#define B_SZ   2048
#define IN_SZ  1024
#define OUT_SZ 1024
#define Q_SZ   16
#define K_EXP  (Q_SZ * IN_SZ)   // 16384

typedef __attribute__((ext_vector_type(8))) short short8;   // 8 bf16 (4 VGPRs)
typedef __attribute__((ext_vector_type(4))) float floatx4;  // MFMA accumulator

__device__ __forceinline__ unsigned short f32_to_bf16_rne(float f) {
    union { float f; uint32_t u; } v; v.f = f;
    uint32_t u = v.u;
    return (unsigned short)((u + 0x7FFFu + ((u >> 16) & 1u)) >> 16);
}

__device__ __forceinline__ void gll16(const void* g, void* l) {
    // async global->LDS, 16B/lane; LDS dst is wave-uniform base + lane*16
    __builtin_amdgcn_global_load_lds(
        (const __attribute__((address_space(1))) void*)g,
        (__attribute__((address_space(3))) void*)l, 16, 0, 0);
}

// ---------------- prep 1: out[b][o] = bias[o] ----------------
__global__ void k_init_out(float* __restrict__ out, const float* __restrict__ bias) {
    int t = blockIdx.x * 256 + threadIdx.x;        // float4 index, 524288 total
    const float4* b4 = (const float4*)bias;
    ((float4*)out)[t] = b4[t & 255];               // 256 float4 per row of 1024
}

// ---------------- prep 2: A_exp[b][q*IN+i] = (idx==q) ? bf16(x) : 0 ----------------
__global__ void k_build_a(const float* __restrict__ x, const int* __restrict__ idx,
                          unsigned short* __restrict__ A) {
    int t = blockIdx.x * 256 + threadIdx.x;        // 262144 threads, 8 i's each
    int b  = t >> 7;
    int ic = (t & 127) << 3;
    const float* xp = x + (size_t)b * IN_SZ + ic;
    const int*   ip = idx + (size_t)b * IN_SZ + ic;
    float xv[8]; int iv[8];
    *(float4*)(xv)     = ((const float4*)xp)[0];
    *(float4*)(xv + 4) = ((const float4*)xp)[1];
    *(int4*)(iv)       = ((const int4*)ip)[0];
    *(int4*)(iv + 4)   = ((const int4*)ip)[1];
    unsigned short bf[8];
#pragma unroll
    for (int j = 0; j < 8; ++j) bf[j] = f32_to_bf16_rne(xv[j]);
    unsigned short* Ab = A + (size_t)b * K_EXP + ic;
#pragma unroll
    for (int q = 0; q < Q_SZ; ++q) {
        unsigned short ov[8];
#pragma unroll
        for (int j = 0; j < 8; ++j) ov[j] = (iv[j] == q) ? bf[j] : (unsigned short)0;
        *(uint4*)(Ab + q * IN_SZ) = *(uint4*)ov;   // 16B aligned (ic mult of 8)
    }
}

// ---------------- prep 3: Wt[o][q*IN+i] = bf16(W[q*IN+i][o])  (transpose+convert) ----
__global__ void k_build_wt(const float* __restrict__ W, unsigned short* __restrict__ Wt) {
    __shared__ float tile[64][65];                 // +1 pad breaks bank conflicts
    int t = threadIdx.x;
    int k0 = blockIdx.x * 64;                      // 256 k-tiles
    int o0 = blockIdx.y * 64;                      // 16 o-tiles
#pragma unroll
    for (int it = 0; it < 4; ++it) {
        int F = it * 256 + t;                      // 1024 float4 loads
        int row = F >> 4;
        int c4  = (F & 15) * 4;
        float4 v = *(const float4*)(W + (size_t)(k0 + row) * OUT_SZ + o0 + c4);
        tile[row][c4 + 0] = v.x; tile[row][c4 + 1] = v.y;
        tile[row][c4 + 2] = v.z; tile[row][c4 + 3] = v.w;
    }
    __syncthreads();
#pragma unroll
    for (int it = 0; it < 2; ++it) {
        int G = it * 256 + t;                      // 512 uint4 stores
        int oo = G >> 3;
        int kc = (G & 7) * 8;
        unsigned short ov[8];
#pragma unroll
        for (int j = 0; j < 8; ++j) ov[j] = f32_to_bf16_rne(tile[kc + j][oo]);
        *(uint4*)(Wt + (size_t)(o0 + oo) * K_EXP + k0 + kc) = *(uint4*)ov;
    }
}

// ---------------- main GEMM: out += A_exp @ Wt^T, split-K=8, atomic epilogue --------
#define KSPLIT 8
#define KPER   (K_EXP / KSPLIT)                    // 2048 -> 64 k-steps of 32

__global__ __launch_bounds__(256, 4) void k_gemm(const unsigned short* __restrict__ A,
                                                 const unsigned short* __restrict__ Wt,
                                                 float* __restrict__ out) {
    __shared__ unsigned short Alds[128 * 32];      // 8 KB, rows of 64B (k-contig)
    __shared__ unsigned short Blds[128 * 32];      // 8 KB
    int tid  = threadIdx.x;
    int wave = tid >> 6, lane = tid & 63;
    int wm = wave & 1, wn = wave >> 1;             // 2x2 wave grid, 64x64 each

    // 1-D grid decode: id = x + 8*z + 64*y. Blocks sharing a Wt tile (same x,z)
    // differ by 64 in id -> same XCD (id%8) -> L2 reuse of the 512 KB Wt slab.
    int id = blockIdx.x;
    int xb = id & 7;
    int zb = (id >> 3) & 7;
    int yb = id >> 6;
    int b0 = yb * 128;
    int o0 = xb * 128;
    int kbase = zb * KPER;

    // staging: lane -> LDS slot (row r0 = wave*16 + lane>>2, slot = lane&3).
    // XOR swizzle: slot s holds global chunk s ^ (r&3)  (chunk = 16B = 8 bf16)
    int r0 = wave * 16 + (lane >> 2);
    int cs = (lane & 3) ^ ((lane >> 2) & 3);       // swizzled source chunk
    const unsigned short* aSrc0 = A  + (size_t)(b0 + r0) * K_EXP + cs * 8 + kbase;
    const unsigned short* aSrc1 = aSrc0 + (size_t)64 * K_EXP;   // r+64: (r&3) same
    const unsigned short* bSrc0 = Wt + (size_t)(o0 + r0) * K_EXP + cs * 8 + kbase;
    const unsigned short* bSrc1 = bSrc0 + (size_t)64 * K_EXP;
    char* aDst0 = (char*)Alds + wave * 1024;       // wave-uniform LDS bases
    char* aDst1 = aDst0 + 4096;
    char* bDst0 = (char*)Blds + wave * 1024;
    char* bDst1 = bDst0 + 4096;

    floatx4 acc[16];
#pragma unroll
    for (int i = 0; i < 16; ++i) acc[i] = (floatx4){0.f, 0.f, 0.f, 0.f};

    // fragment reads: A[m=lane&15][k=quad*8+j]; with swizzle the quad chunk for
    // row r lives at slot quad ^ (r&3), r&3 == lane&3
    const char* aB = (const char*)Alds;
    const char* bB = (const char*)Blds;
    int qs = ((lane >> 4) ^ (lane & 3)) * 16;      // swizzled chunk byte offset
    int aoff[4], boff[4];
#pragma unroll
    for (int mt = 0; mt < 4; ++mt)
        aoff[mt] = (wm * 64 + mt * 16 + (lane & 15)) * 64 + qs;
#pragma unroll
    for (int nt = 0; nt < 4; ++nt)
        boff[nt] = (wn * 64 + nt * 16 + (lane & 15)) * 64 + qs;

    for (int step = 0; step < KPER / 32; ++step) {
        int ko = step * 32;
        gll16(aSrc0 + ko, aDst0);
        gll16(aSrc1 + ko, aDst1);
        gll16(bSrc0 + ko, bDst0);
        gll16(bSrc1 + ko, bDst1);
        __syncthreads();                            // drains vmcnt before barrier
        short8 aF[4], bF[4];
#pragma unroll
        for (int mt = 0; mt < 4; ++mt) aF[mt] = *(const short8*)(aB + aoff[mt]);
#pragma unroll
        for (int nt = 0; nt < 4; ++nt) bF[nt] = *(const short8*)(bB + boff[nt]);
#pragma unroll
        for (int mt = 0; mt < 4; ++mt)
#pragma unroll
            for (int nt = 0; nt < 4; ++nt)
                acc[mt * 4 + nt] = __builtin_amdgcn_mfma_f32_16x16x32_bf16(
                    aF[mt], bF[nt], acc[mt * 4 + nt], 0, 0, 0);
        __syncthreads();
    }

    // epilogue: C/D layout col=lane&15 (o), row=(lane>>4)*4+reg (b)
    int cn = lane & 15, rq = lane >> 4;
#pragma unroll
    for (int mt = 0; mt < 4; ++mt)
#pragma unroll
        for (int nt = 0; nt < 4; ++nt) {
            int bb = b0 + wm * 64 + mt * 16 + rq * 4;
            int oo = o0 + wn * 64 + nt * 16 + cn;
#pragma unroll
            for (int e = 0; e < 4; ++e)
                atomicAdd(out + (size_t)(bb + e) * OUT_SZ + oo, acc[mt * 4 + nt][e]);
        }
}

// ---------------- fallback (ws too small): exact fp32 gather ----------------
__global__ void k_naive(const float* __restrict__ x, const int* __restrict__ idx,
                        const float* __restrict__ W, const float* __restrict__ bias,
                        float* __restrict__ out) {
    int b = blockIdx.x;
    int o = threadIdx.x * 4;
    float4 acc = *(const float4*)(bias + o);
    const float* xr = x + (size_t)b * IN_SZ;
    const int*   ir = idx + (size_t)b * IN_SZ;
    for (int i = 0; i < IN_SZ; ++i) {
        float xv = xr[i];
        int q = ir[i];
        float4 w4 = *(const float4*)(W + ((size_t)q * IN_SZ + i) * OUT_SZ + o);
        acc.x += xv * w4.x; acc.y += xv * w4.y;
        acc.z += xv * w4.z; acc.w += xv * w4.w;
    }
    *(float4*)(out + (size_t)b * OUT_SZ + o) = acc;
}

extern "C" void kernel_launch(void* const* d_in, const int* in_sizes, int n_in,
                              void* d_out, int out_size, void* d_ws, size_t ws_size,
                              hipStream_t stream) {
    const float* x    = (const float*)d_in[0];
    const int*   idx  = (const int*)d_in[1];
    const float* W    = (const float*)d_in[2];
    const float* bias = (const float*)d_in[3];
    float* out = (float*)d_out;

    const size_t wt_elems = (size_t)OUT_SZ * K_EXP;          // 16M ushorts = 32 MB
    const size_t a_elems  = (size_t)B_SZ * K_EXP;            // 32M ushorts = 64 MB
    if (ws_size < (wt_elems + a_elems) * sizeof(unsigned short)) {
        k_naive<<<dim3(B_SZ), dim3(256), 0, stream>>>(x, idx, W, bias, out);
        return;
    }
    unsigned short* Wt = (unsigned short*)d_ws;
    unsigned short* A  = Wt + wt_elems;

    k_init_out<<<dim3(2048), dim3(256), 0, stream>>>(out, bias);
    k_build_a<<<dim3(1024), dim3(256), 0, stream>>>(x, idx, A);
    k_build_wt<<<dim3(256, 16), dim3(256), 0, stream>>>(W, Wt);
    k_gemm<<<dim3((OUT_SZ / 128) * (B_SZ / 128) * KSPLIT), dim3(256), 0, stream>>>(A, Wt, out);
}

// Round 3
// 257.190 us; speedup vs baseline: 1.0303x; 1.0222x over previous
//
#include <hip/hip_runtime.h>
#include <stdint.h>

#define B_SZ   2048
#define IN_SZ  1024
#define OUT_SZ 1024
#define Q_SZ   16
#define K_EXP  (Q_SZ * IN_SZ)   // 16384

typedef __attribute__((ext_vector_type(8))) short short8;   // 8 bf16 (4 VGPRs)
typedef __attribute__((ext_vector_type(4))) float floatx4;  // MFMA accumulator

__device__ __forceinline__ unsigned short f32_to_bf16_rne(float f) {
    union { float f; uint32_t u; } v; v.f = f;
    uint32_t u = v.u;
    return (unsigned short)((u + 0x7FFFu + ((u >> 16) & 1u)) >> 16);
}

__device__ __forceinline__ void gll16(const void* g, void* l) {
    // async global->LDS, 16B/lane; LDS dst is wave-uniform base + lane*16
    __builtin_amdgcn_global_load_lds(
        (const __attribute__((address_space(1))) void*)g,
        (__attribute__((address_space(3))) void*)l, 16, 0, 0);
}

// ---------------- prep 1: out[b][o] = bias[o] ----------------
__global__ void k_init_out(float* __restrict__ out, const float* __restrict__ bias) {
    int t = blockIdx.x * 256 + threadIdx.x;        // float4 index, 524288 total
    const float4* b4 = (const float4*)bias;
    ((float4*)out)[t] = b4[t & 255];               // 256 float4 per row of 1024
}

// ---------------- prep 2: A_exp[b][q*IN+i] = (idx==q) ? bf16(x) : 0 ----------------
__global__ void k_build_a(const float* __restrict__ x, const int* __restrict__ idx,
                          unsigned short* __restrict__ A) {
    int t = blockIdx.x * 256 + threadIdx.x;        // 262144 threads, 8 i's each
    int b  = t >> 7;
    int ic = (t & 127) << 3;
    const float* xp = x + (size_t)b * IN_SZ + ic;
    const int*   ip = idx + (size_t)b * IN_SZ + ic;
    float xv[8]; int iv[8];
    *(float4*)(xv)     = ((const float4*)xp)[0];
    *(float4*)(xv + 4) = ((const float4*)xp)[1];
    *(int4*)(iv)       = ((const int4*)ip)[0];
    *(int4*)(iv + 4)   = ((const int4*)ip)[1];
    unsigned short bf[8];
#pragma unroll
    for (int j = 0; j < 8; ++j) bf[j] = f32_to_bf16_rne(xv[j]);
    unsigned short* Ab = A + (size_t)b * K_EXP + ic;
#pragma unroll
    for (int q = 0; q < Q_SZ; ++q) {
        unsigned short ov[8];
#pragma unroll
        for (int j = 0; j < 8; ++j) ov[j] = (iv[j] == q) ? bf[j] : (unsigned short)0;
        *(uint4*)(Ab + q * IN_SZ) = *(uint4*)ov;   // 16B aligned (ic mult of 8)
    }
}

// ---------------- prep 3: Wt[o][q*IN+i] = bf16(W[q*IN+i][o])  (transpose+convert) ----
__global__ void k_build_wt(const float* __restrict__ W, unsigned short* __restrict__ Wt) {
    __shared__ float tile[64][65];                 // +1 pad breaks bank conflicts
    int t = threadIdx.x;
    int k0 = blockIdx.x * 64;                      // 256 k-tiles
    int o0 = blockIdx.y * 64;                      // 16 o-tiles
#pragma unroll
    for (int it = 0; it < 4; ++it) {
        int F = it * 256 + t;                      // 1024 float4 loads
        int row = F >> 4;
        int c4  = (F & 15) * 4;
        float4 v = *(const float4*)(W + (size_t)(k0 + row) * OUT_SZ + o0 + c4);
        tile[row][c4 + 0] = v.x; tile[row][c4 + 1] = v.y;
        tile[row][c4 + 2] = v.z; tile[row][c4 + 3] = v.w;
    }
    __syncthreads();
#pragma unroll
    for (int it = 0; it < 2; ++it) {
        int G = it * 256 + t;                      // 512 uint4 stores
        int oo = G >> 3;
        int kc = (G & 7) * 8;
        unsigned short ov[8];
#pragma unroll
        for (int j = 0; j < 8; ++j) ov[j] = f32_to_bf16_rne(tile[kc + j][oo]);
        *(uint4*)(Wt + (size_t)(o0 + oo) * K_EXP + k0 + kc) = *(uint4*)ov;
    }
}

// ---------------- main GEMM: out += A_exp @ Wt^T, split-K=8, BK=64 ----------------
#define KSPLIT 8
#define KPER   (K_EXP / KSPLIT)                    // 2048
#define BK     64
#define NSTEP  (KPER / BK)                         // 32 k-steps per block

// LDS tile: 128 rows x 64 bf16 = 128 B rows = 8 chunks of 16 B.
// XOR swizzle: chunk (row, c) stored at slot c ^ (row & 7) -> bank-spread reads.
__global__ __launch_bounds__(256, 4) void k_gemm(const unsigned short* __restrict__ A,
                                                 const unsigned short* __restrict__ Wt,
                                                 float* __restrict__ out) {
    __shared__ unsigned short Alds[128 * BK];      // 16 KB
    __shared__ unsigned short Blds[128 * BK];      // 16 KB
    int tid  = threadIdx.x;
    int wave = tid >> 6, lane = tid & 63;
    int wm = wave & 1, wn = wave >> 1;             // 2x2 wave grid, 64x64 each

    // 1-D grid decode: id = x + 8*z + 64*y -> blocks sharing Wt o-slab (same x)
    // land on the same XCD (id%8 == x) for L2 reuse; split-K partners too.
    int id = blockIdx.x;
    int xb = id & 7;
    int zb = (id >> 3) & 7;
    int yb = id >> 6;
    int b0 = yb * 128;
    int o0 = xb * 128;
    int kbase = zb * KPER;

    // staging: wave w covers rows [w*32, w*32+32), 8 chunks/row, via 4 gll16
    // per matrix. lane -> (row = w*32 + g*8 + lane>>3, slot = lane&7).
    // source chunk col = slot ^ (row&7) = (lane&7) ^ (lane>>3).
    int lrow = lane >> 3;                          // 0..7
    int lcol = lane & 7;
    int scol = lcol ^ lrow;                        // swizzled source chunk
    const unsigned short* aS = A  + (size_t)(b0 + wave * 32 + lrow) * K_EXP + kbase + scol * 8;
    const unsigned short* bS = Wt + (size_t)(o0 + wave * 32 + lrow) * K_EXP + kbase + scol * 8;
    char* aD = (char*)Alds + wave * 4096;          // wave-uniform LDS bases
    char* bD = (char*)Blds + wave * 4096;

    floatx4 acc[16];
#pragma unroll
    for (int i = 0; i < 16; ++i) acc[i] = (floatx4){0.f, 0.f, 0.f, 0.f};

    // fragment reads: A[m=lane&15][k = h*32 + (lane>>4)*8 + j]
    // chunk c = h*4 + quad lives at slot c ^ (m&7); m&7 == lane&7.
    int mb[4], nb[4];
#pragma unroll
    for (int mt = 0; mt < 4; ++mt)
        mb[mt] = (wm * 64 + mt * 16 + (lane & 15)) * 128;
#pragma unroll
    for (int nt = 0; nt < 4; ++nt)
        nb[nt] = (wn * 64 + nt * 16 + (lane & 15)) * 128;
    int so[2];
#pragma unroll
    for (int h = 0; h < 2; ++h)
        so[h] = (((h << 2) | (lane >> 4)) ^ lcol) * 16;

    const char* aB = (const char*)Alds;
    const char* bB = (const char*)Blds;

    for (int step = 0; step < NSTEP; ++step) {
        size_t ko = (size_t)step * BK;
#pragma unroll
        for (int g = 0; g < 4; ++g) {
            gll16(aS + ko + (size_t)g * 8 * K_EXP, aD + g * 1024);
            gll16(bS + ko + (size_t)g * 8 * K_EXP, bD + g * 1024);
        }
        __syncthreads();                            // drains vmcnt before barrier
#pragma unroll
        for (int h = 0; h < 2; ++h) {
            short8 aF[4], bF[4];
#pragma unroll
            for (int mt = 0; mt < 4; ++mt) aF[mt] = *(const short8*)(aB + mb[mt] + so[h]);
#pragma unroll
            for (int nt = 0; nt < 4; ++nt) bF[nt] = *(const short8*)(bB + nb[nt] + so[h]);
#pragma unroll
            for (int mt = 0; mt < 4; ++mt)
#pragma unroll
                for (int nt = 0; nt < 4; ++nt)
                    acc[mt * 4 + nt] = __builtin_amdgcn_mfma_f32_16x16x32_bf16(
                        aF[mt], bF[nt], acc[mt * 4 + nt], 0, 0, 0);
        }
        __syncthreads();
    }

    // epilogue: C/D layout col=lane&15 (o), row=(lane>>4)*4+reg (b)
    int cn = lane & 15, rq = lane >> 4;
#pragma unroll
    for (int mt = 0; mt < 4; ++mt)
#pragma unroll
        for (int nt = 0; nt < 4; ++nt) {
            int bb = b0 + wm * 64 + mt * 16 + rq * 4;
            int oo = o0 + wn * 64 + nt * 16 + cn;
#pragma unroll
            for (int e = 0; e < 4; ++e)
                atomicAdd(out + (size_t)(bb + e) * OUT_SZ + oo, acc[mt * 4 + nt][e]);
        }
}

// ---------------- fallback (ws too small): exact fp32 gather ----------------
__global__ void k_naive(const float* __restrict__ x, const int* __restrict__ idx,
                        const float* __restrict__ W, const float* __restrict__ bias,
                        float* __restrict__ out) {
    int b = blockIdx.x;
    int o = threadIdx.x * 4;
    float4 acc = *(const float4*)(bias + o);
    const float* xr = x + (size_t)b * IN_SZ;
    const int*   ir = idx + (size_t)b * IN_SZ;
    for (int i = 0; i < IN_SZ; ++i) {
        float xv = xr[i];
        int q = ir[i];
        float4 w4 = *(const float4*)(W + ((size_t)q * IN_SZ + i) * OUT_SZ + o);
        acc.x += xv * w4.x; acc.y += xv * w4.y;
        acc.z += xv * w4.z; acc.w += xv * w4.w;
    }
    *(float4*)(out + (size_t)b * OUT_SZ + o) = acc;
}

extern "C" void kernel_launch(void* const* d_in, const int* in_sizes, int n_in,
                              void* d_out, int out_size, void* d_ws, size_t ws_size,
                              hipStream_t stream) {
    const float* x    = (const float*)d_in[0];
    const int*   idx  = (const int*)d_in[1];
    const float* W    = (const float*)d_in[2];
    const float* bias = (const float*)d_in[3];
    float* out = (float*)d_out;

    const size_t wt_elems = (size_t)OUT_SZ * K_EXP;          // 16M ushorts = 32 MB
    const size_t a_elems  = (size_t)B_SZ * K_EXP;            // 32M ushorts = 64 MB
    if (ws_size < (wt_elems + a_elems) * sizeof(unsigned short)) {
        k_naive<<<dim3(B_SZ), dim3(256), 0, stream>>>(x, idx, W, bias, out);
        return;
    }
    unsigned short* Wt = (unsigned short*)d_ws;
    unsigned short* A  = Wt + wt_elems;

    k_init_out<<<dim3(2048), dim3(256), 0, stream>>>(out, bias);
    k_build_a<<<dim3(1024), dim3(256), 0, stream>>>(x, idx, A);
    k_build_wt<<<dim3(256, 16), dim3(256), 0, stream>>>(W, Wt);
    k_gemm<<<dim3((OUT_SZ / 128) * (B_SZ / 128) * KSPLIT), dim3(256), 0, stream>>>(A, Wt, out);
}

// Round 4
// 228.284 us; speedup vs baseline: 1.1607x; 1.1266x over previous
//
#include <hip/hip_runtime.h>
#include <stdint.h>

#define B_SZ   2048
#define IN_SZ  1024
#define OUT_SZ 1024
#define Q_SZ   16
#define K_EXP  (Q_SZ * IN_SZ)   // 16384

typedef __attribute__((ext_vector_type(8))) short short8;   // 8 bf16 (4 VGPRs)
typedef __attribute__((ext_vector_type(4))) float floatx4;  // MFMA accumulator

__device__ __forceinline__ unsigned short f32_to_bf16_rne(float f) {
    union { float f; uint32_t u; } v; v.f = f;
    uint32_t u = v.u;
    return (unsigned short)((u + 0x7FFFu + ((u >> 16) & 1u)) >> 16);
}

__device__ __forceinline__ void gll16(const void* g, void* l) {
    // async global->LDS, 16B/lane; LDS dst is wave-uniform base + lane*16
    __builtin_amdgcn_global_load_lds(
        (const __attribute__((address_space(1))) void*)g,
        (__attribute__((address_space(3))) void*)l, 16, 0, 0);
}

// packed 2x16-bit: out = (iv16==q16) ? xv16 : 0.  Valid because iv,q < 16 so
// t = iv^qq has halves in [0,32): 0x8000 - t never borrows across halves.
__device__ __forceinline__ uint32_t mask2(uint32_t xv, uint32_t iv, uint32_t qq) {
    uint32_t t = iv ^ qq;
    uint32_t m = (0x80008000u - t) & 0x80008000u;   // bit15/31 set iff half==q
    uint32_t f = m | (m - (m >> 15));               // spread to 0xFFFF per half
    return xv & f;
}

// ---------------- prep 1: out[b][o] = bias[o] ----------------
__global__ void k_init_out(float* __restrict__ out, const float* __restrict__ bias) {
    int t = blockIdx.x * 256 + threadIdx.x;        // float4 index, 524288 total
    const float4* b4 = (const float4*)bias;
    ((float4*)out)[t] = b4[t & 255];               // 256 float4 per row of 1024
}

// ---------------- prep 2: x -> bf16, idx -> u16 ----------------
__global__ void k_prep_xi(const float* __restrict__ x, const int* __restrict__ idx,
                          unsigned short* __restrict__ xb16, unsigned short* __restrict__ idxh) {
    int t = blockIdx.x * 256 + threadIdx.x;        // 262144 threads, 8 elems each
    int b  = t >> 7;
    int c  = (t & 127) << 3;
    const float* xp = x + (size_t)b * IN_SZ + c;
    const int*   ip = idx + (size_t)b * IN_SZ + c;
    float xv[8]; int iv[8];
    *(float4*)(xv)     = ((const float4*)xp)[0];
    *(float4*)(xv + 4) = ((const float4*)xp)[1];
    *(int4*)(iv)       = ((const int4*)ip)[0];
    *(int4*)(iv + 4)   = ((const int4*)ip)[1];
    unsigned short xo[8], io8[8];
#pragma unroll
    for (int j = 0; j < 8; ++j) { xo[j] = f32_to_bf16_rne(xv[j]); io8[j] = (unsigned short)iv[j]; }
    *(uint4*)(xb16 + (size_t)b * IN_SZ + c) = *(uint4*)xo;
    *(uint4*)(idxh + (size_t)b * IN_SZ + c) = *(uint4*)io8;
}

// ---------------- prep 3: Wt[o][q*IN+i] = bf16(W[q*IN+i][o])  (transpose+convert) ----
__global__ void k_build_wt(const float* __restrict__ W, unsigned short* __restrict__ Wt) {
    __shared__ float tile[64][65];                 // +1 pad breaks bank conflicts
    int t = threadIdx.x;
    int k0 = blockIdx.x * 64;                      // 256 k-tiles
    int o0 = blockIdx.y * 64;                      // 16 o-tiles
#pragma unroll
    for (int it = 0; it < 4; ++it) {
        int F = it * 256 + t;                      // 1024 float4 loads
        int row = F >> 4;
        int c4  = (F & 15) * 4;
        float4 v = *(const float4*)(W + (size_t)(k0 + row) * OUT_SZ + o0 + c4);
        tile[row][c4 + 0] = v.x; tile[row][c4 + 1] = v.y;
        tile[row][c4 + 2] = v.z; tile[row][c4 + 3] = v.w;
    }
    __syncthreads();
#pragma unroll
    for (int it = 0; it < 2; ++it) {
        int G = it * 256 + t;                      // 512 uint4 stores
        int oo = G >> 3;
        int kc = (G & 7) * 8;
        unsigned short ov[8];
#pragma unroll
        for (int j = 0; j < 8; ++j) ov[j] = f32_to_bf16_rne(tile[kc + j][oo]);
        *(uint4*)(Wt + (size_t)(o0 + oo) * K_EXP + k0 + kc) = *(uint4*)ov;
    }
}

// ---------------- fused GEMM: out += maskq(x) @ Wt^T over the block's i-window ----
// z-block owns i in [zb*128, zb*128+128), ALL q. 32 steps = 2 i-halves x 16 q.
// Only Wt is LDS-staged (16 KB/step, ping-pong, ONE barrier per step); x/idx live
// in registers (reloaded per i-half straight from global, full-line coalesced).
// Wave tile: 32 b-rows x 128 o-cols (2 mt x 8 nt of 16x16x32 MFMA).
__global__ __launch_bounds__(256, 3) void k_gemm(const unsigned short* __restrict__ Wt,
                                                 const unsigned short* __restrict__ xb16,
                                                 const unsigned short* __restrict__ idxh,
                                                 float* __restrict__ out) {
    __shared__ unsigned short Blds[2 * 128 * 64];  // 32 KB ping-pong
    const int tid  = threadIdx.x;
    const int wave = tid >> 6, lane = tid & 63;

    // 1-D grid, id = zb + 8*xb + 64*yb -> XCD (id%8) = zb: all blocks on one XCD
    // share the same Wt column window (4 MB = exactly one XCD L2).
    const int id = blockIdx.x;
    const int zb = id & 7;
    const int o0 = ((id >> 3) & 7) * 128;
    const int b0 = (id >> 6) * 128;
    const int ibase = zb * 128;                    // i-window

    // Wt staging: wave w rows [w*32+g*8+lrow], 128B rows = 8 chunks, slot = c^(row&7)
    const int lrow = lane >> 3, lcol = lane & 7;
    const int scol = lcol ^ lrow;
    const unsigned short* wS = Wt + (size_t)(o0 + wave * 32 + lrow) * K_EXP + ibase + scol * 8;
    char* wDb = (char*)Blds + wave * 4096;

    // B-frag offsets: row = nt*16 + (lane&15); chunk c = h*4 + quad at slot c^(lane&7)
    int nb[8];
#pragma unroll
    for (int nt = 0; nt < 8; ++nt) nb[nt] = (nt * 16 + (lane & 15)) * 128;
    int so[2];
#pragma unroll
    for (int h = 0; h < 2; ++h) so[h] = (((h << 2) | (lane >> 4)) ^ lcol) * 16;

    // A-side: row b0 + wave*32 + mt*16 + (lane&15); k-bytes per (h,quad) cover a full line
    const int arow = b0 + wave * 32 + (lane & 15);
    const unsigned short* xg = xb16 + (size_t)arow * IN_SZ + ibase + (lane >> 4) * 8;
    const unsigned short* ig = idxh + (size_t)arow * IN_SZ + ibase + (lane >> 4) * 8;

    floatx4 acc[16];
#pragma unroll
    for (int i = 0; i < 16; ++i) acc[i] = (floatx4){0.f, 0.f, 0.f, 0.f};

    // stage step s into buf (s&1): Wt cols (s&15)*1024 + (s>>4)*64 within window
#define STAGE(s)                                                              \
    {   int cw_ = ((s) & 15) * 1024 + (((s) >> 4) & 1) * 64;                  \
        char* d_ = wDb + (((s) & 1) << 14);                                   \
        _Pragma("unroll")                                                     \
        for (int g_ = 0; g_ < 4; ++g_)                                        \
            gll16(wS + cw_ + (size_t)g_ * 8 * K_EXP, d_ + g_ * 1024);         \
    }

    STAGE(0);
    uint4 xr[2][2], ir[2][2];

    for (int s = 0; s < 32; ++s) {
        __syncthreads();                           // buf[s&1] staged & prior readers done
        if (s < 31) STAGE(s + 1);                  // lands during compute(s)
        if ((s & 15) == 0) {                       // new i-half: reload A regs (uniform)
            int io = (s >> 4) * 64;
#pragma unroll
            for (int mt = 0; mt < 2; ++mt)
#pragma unroll
                for (int h = 0; h < 2; ++h) {
                    xr[mt][h] = *(const uint4*)(xg + mt * 16 * IN_SZ + io + h * 32);
                    ir[mt][h] = *(const uint4*)(ig + mt * 16 * IN_SZ + io + h * 32);
                }
        }
        const uint32_t qq = (uint32_t)(s & 15) * 0x00010001u;
        const char* bB = (const char*)Blds + ((s & 1) << 14);
#pragma unroll
        for (int h = 0; h < 2; ++h) {
            union { uint4 u; short8 s8; } aF[2];
#pragma unroll
            for (int mt = 0; mt < 2; ++mt) {
                aF[mt].u.x = mask2(xr[mt][h].x, ir[mt][h].x, qq);
                aF[mt].u.y = mask2(xr[mt][h].y, ir[mt][h].y, qq);
                aF[mt].u.z = mask2(xr[mt][h].z, ir[mt][h].z, qq);
                aF[mt].u.w = mask2(xr[mt][h].w, ir[mt][h].w, qq);
            }
            short8 bF[8];
#pragma unroll
            for (int nt = 0; nt < 8; ++nt) bF[nt] = *(const short8*)(bB + nb[nt] + so[h]);
#pragma unroll
            for (int mt = 0; mt < 2; ++mt)
#pragma unroll
                for (int nt = 0; nt < 8; ++nt)
                    acc[mt * 8 + nt] = __builtin_amdgcn_mfma_f32_16x16x32_bf16(
                        aF[mt].s8, bF[nt], acc[mt * 8 + nt], 0, 0, 0);
        }
        // single barrier per step: next iteration's barrier protects buf reuse
    }

    // epilogue: C/D col=lane&15 (o), row=(lane>>4)*4+reg (b)
    int cn = lane & 15, rq = lane >> 4;
#pragma unroll
    for (int mt = 0; mt < 2; ++mt)
#pragma unroll
        for (int nt = 0; nt < 8; ++nt) {
            int bb = b0 + wave * 32 + mt * 16 + rq * 4;
            int oo = o0 + nt * 16 + cn;
#pragma unroll
            for (int e = 0; e < 4; ++e)
                atomicAdd(out + (size_t)(bb + e) * OUT_SZ + oo, acc[mt * 8 + nt][e]);
        }
#undef STAGE
}

// ---------------- fallback (ws too small): exact fp32 gather ----------------
__global__ void k_naive(const float* __restrict__ x, const int* __restrict__ idx,
                        const float* __restrict__ W, const float* __restrict__ bias,
                        float* __restrict__ out) {
    int b = blockIdx.x;
    int o = threadIdx.x * 4;
    float4 acc = *(const float4*)(bias + o);
    const float* xr = x + (size_t)b * IN_SZ;
    const int*   ir = idx + (size_t)b * IN_SZ;
    for (int i = 0; i < IN_SZ; ++i) {
        float xv = xr[i];
        int q = ir[i];
        float4 w4 = *(const float4*)(W + ((size_t)q * IN_SZ + i) * OUT_SZ + o);
        acc.x += xv * w4.x; acc.y += xv * w4.y;
        acc.z += xv * w4.z; acc.w += xv * w4.w;
    }
    *(float4*)(out + (size_t)b * OUT_SZ + o) = acc;
}

extern "C" void kernel_launch(void* const* d_in, const int* in_sizes, int n_in,
                              void* d_out, int out_size, void* d_ws, size_t ws_size,
                              hipStream_t stream) {
    const float* x    = (const float*)d_in[0];
    const int*   idx  = (const int*)d_in[1];
    const float* W    = (const float*)d_in[2];
    const float* bias = (const float*)d_in[3];
    float* out = (float*)d_out;

    const size_t wt_elems = (size_t)OUT_SZ * K_EXP;          // 16M u16 = 32 MB
    const size_t x_elems  = (size_t)B_SZ * IN_SZ;            // 2M u16 = 4 MB
    if (ws_size < (wt_elems + 2 * x_elems) * sizeof(unsigned short)) {
        k_naive<<<dim3(B_SZ), dim3(256), 0, stream>>>(x, idx, W, bias, out);
        return;
    }
    unsigned short* Wt   = (unsigned short*)d_ws;
    unsigned short* xb16 = Wt + wt_elems;
    unsigned short* idxh = xb16 + x_elems;

    k_init_out<<<dim3(2048), dim3(256), 0, stream>>>(out, bias);
    k_prep_xi<<<dim3(1024), dim3(256), 0, stream>>>(x, idx, xb16, idxh);
    k_build_wt<<<dim3(256, 16), dim3(256), 0, stream>>>(W, Wt);
    k_gemm<<<dim3(8 * 8 * (B_SZ / 128)), dim3(256), 0, stream>>>(Wt, xb16, idxh, out);
}